// Round 4
// baseline (248.740 us; speedup 1.0000x reference)
//
#include <hip/hip_runtime.h>
#include <hip/hip_bf16.h>
#include <math.h>

// Problem sizes (fixed by reference): B=256, M=64, N=32, D=128, T=64, L=128
#define B_ 256
#define M_ 64
#define N_ 32
#define D_ 128
#define T_ 64
#define L_ 128

typedef __attribute__((ext_vector_type(8))) short short8;   // 8 bf16 = 4 VGPRs (MFMA A/B frag)
typedef __attribute__((ext_vector_type(4))) float floatx4;  // MFMA C/D frag

__device__ __forceinline__ unsigned short f2bf(float f) {
  unsigned int u = __float_as_uint(f);
  unsigned int r = (u + 0x7fffu + ((u >> 16) & 1u)) >> 16;  // RNE
  return (unsigned short)r;
}
__device__ __forceinline__ float bf2f(unsigned short s) {
  return __uint_as_float(((unsigned int)s) << 16);
}
__device__ __forceinline__ float frcp(float x) { return __builtin_amdgcn_rcpf(x); }
// packed 2x f32 -> bf16x2 (low = a, high = b); lowers to HW packed cvt on gfx950
__device__ __forceinline__ unsigned pk2bf(float a, float b) {
  __hip_bfloat162 h = __float22bfloat162_rn(make_float2(a, b));
  unsigned u;
  __builtin_memcpy(&u, &h, 4);
  return u;
}

// ---------------------------------------------------------------------------
// DPP 16-lane reductions (lane bits 0-3 == DPP row). row_ror:{1,2,4,8} chain
// gives every lane the full 16-lane result at VALU rate — replaces the
// ds_bpermute ladders __shfl_xor(x, 1/2/4/8) would emit (~40cy each, LDS pipe).
// ---------------------------------------------------------------------------
template <int CTRL>
__device__ __forceinline__ float dpp_f(float x) {
  return __int_as_float(__builtin_amdgcn_update_dpp(
      __float_as_int(x), __float_as_int(x), CTRL, 0xf, 0xf, false));
}
__device__ __forceinline__ float rsum16(float x) {
  x += dpp_f<0x121>(x);  // row_ror:1
  x += dpp_f<0x122>(x);  // row_ror:2
  x += dpp_f<0x124>(x);  // row_ror:4
  x += dpp_f<0x128>(x);  // row_ror:8
  return x;
}
__device__ __forceinline__ float rmax16(float x) {
  x = fmaxf(x, dpp_f<0x121>(x));
  x = fmaxf(x, dpp_f<0x122>(x));
  x = fmaxf(x, dpp_f<0x124>(x));
  x = fmaxf(x, dpp_f<0x128>(x));
  return x;
}

// ---------------------------------------------------------------------------
// K0: prep. blocks < 1024: x -> bf16 PI-PERMUTED xb2[m][b][pi(d)],
// pi(16i+j) = 8j+i (matches k_wpriors' entmax weight order -> GEMM dots
// unchanged). block 1024: leaves norm. 1025: thrT.
// ---------------------------------------------------------------------------
__global__ __launch_bounds__(256) void k_prep(const float* __restrict__ x,
                                              const float* __restrict__ leaves,
                                              unsigned short* __restrict__ xb2,
                                              unsigned short* __restrict__ lhn,
                                              const float* __restrict__ thr,
                                              float* __restrict__ thrT) {
  const int tid = threadIdx.x;
  const int bx = blockIdx.x;
  if (bx < 1024) {
    int idx = bx * 256 + tid;          // (m, b, j)
    int j = idx & 15, b = (idx >> 4) & 255, m = idx >> 12;
    const float* xs = x + ((size_t)b * M_ + m) * D_ + j;   // d = 16i + j
    float v[8];
#pragma unroll
    for (int i = 0; i < 8; ++i) v[i] = xs[i * 16];
    unsigned short* dst = xb2 + ((size_t)m * B_ + b) * D_ + j * 8;  // pi pos 8j+i
    uint4 w;
    w.x = pk2bf(v[0], v[1]);
    w.y = pk2bf(v[2], v[3]);
    w.z = pk2bf(v[4], v[5]);
    w.w = pk2bf(v[6], v[7]);
    *(uint4*)dst = w;
  } else if (bx == 1024) {
    if (tid < L_) {
      const float* r = leaves + tid * T_;
      float ss = 0.f;
      for (int i = 0; i < T_; ++i) ss = fmaf(r[i], r[i], ss);
      float inv = frcp(fmaxf(sqrtf(ss), 1e-12f));
      unsigned short* o = lhn + tid * T_;
      for (int i = 0; i < T_; ++i) o[i] = f2bf(r[i] * inv);
    }
  } else {  // thrT[n][m] = thr[m][n]
#pragma unroll
    for (int k = 0; k < 8; ++k) {
      int idx = k * 256 + tid;
      int nn = idx >> 6, mm = idx & 63;
      thrT[idx] = thr[mm * N_ + nn];
    }
  }
}

// ---------------------------------------------------------------------------
// K1 (R19 = R17 verbatim): no Ct buffer, register butterfly transpose,
// 8 blocks/CU, DPP reductions in entmax. R18's program-order weave REGRESSED
// (occupancy 30%, +37MB hbm traffic): on this chip occupancy IS the overlap
// mechanism — do not trade blocks/CU for instruction-level interleaving.
// ---------------------------------------------------------------------------
#define BS_STRIDE 136
__global__ __launch_bounds__(256, 8) void k_wpriors(const unsigned short* __restrict__ xb2,
                                                    const float* __restrict__ rw,
                                                    unsigned short* __restrict__ priors) {
  const int m = blockIdx.x, n = blockIdx.y;
  const int tid = threadIdx.x;
  const int wid = tid >> 6, lane = tid & 63;
  const int row16 = lane & 15, quad = lane >> 4;

  __shared__ __align__(16) unsigned short Bs[64 * BS_STRIDE];  // W [t][pi_k] bf16

  // ---- 1. entmax (direct-global float4-along-T) ----
  {
    const int g = tid >> 4, j = tid & 15;
    const float* base = rw + (size_t)(m * N_ + n) * (D_ * T_) + g * 4;
    floatx4 xv[8];
#pragma unroll
    for (int i = 0; i < 8; ++i)
      xv[i] = *(const floatx4*)(base + (size_t)(i * 16 + j) * T_);

    floatx4 mx = xv[0];
#pragma unroll
    for (int i = 1; i < 8; ++i)
#pragma unroll
      for (int c = 0; c < 4; ++c) mx[c] = fmaxf(mx[c], xv[i][c]);
#pragma unroll
    for (int c = 0; c < 4; ++c) mx[c] = rmax16(mx[c]);
#pragma unroll
    for (int i = 0; i < 8; ++i)
#pragma unroll
      for (int c = 0; c < 4; ++c) xv[i][c] = (xv[i][c] - mx[c]) * 0.5f;

    floatx4 lo = (floatx4){-1.f, -1.f, -1.f, -1.f};
    floatx4 hi = (floatx4){0.f, 0.f, 0.f, 0.f};
    for (int it = 0; it < 8; ++it) {
      floatx4 tau, f = (floatx4){0.f, 0.f, 0.f, 0.f};
#pragma unroll
      for (int c = 0; c < 4; ++c) tau[c] = 0.5f * (lo[c] + hi[c]);
#pragma unroll
      for (int i = 0; i < 8; ++i)
#pragma unroll
        for (int c = 0; c < 4; ++c) {
          float u = fmaxf(xv[i][c] - tau[c], 0.0f);
          f[c] = fmaf(u, u, f[c]);
        }
#pragma unroll
      for (int c = 0; c < 4; ++c) f[c] = rsum16(f[c]);
#pragma unroll
      for (int c = 0; c < 4; ++c) {
        bool ge = f[c] >= 1.0f;
        lo[c] = ge ? tau[c] : lo[c];
        hi[c] = ge ? hi[c] : tau[c];
      }
    }
    floatx4 tau0, cnt = (floatx4){0,0,0,0}, s1 = (floatx4){0,0,0,0}, s2 = (floatx4){0,0,0,0};
#pragma unroll
    for (int c = 0; c < 4; ++c) tau0[c] = 0.5f * (lo[c] + hi[c]);
#pragma unroll
    for (int i = 0; i < 8; ++i)
#pragma unroll
      for (int c = 0; c < 4; ++c) {
        bool in = xv[i][c] > tau0[c];
        float q = in ? xv[i][c] : 0.0f;
        cnt[c] += in ? 1.0f : 0.0f;
        s1[c] += q;
        s2[c] = fmaf(q, q, s2[c]);
      }
#pragma unroll
    for (int c = 0; c < 4; ++c) {
      cnt[c] = rsum16(cnt[c]);
      s1[c] = rsum16(s1[c]);
      s2[c] = rsum16(s2[c]);
    }
    floatx4 tau;
#pragma unroll
    for (int c = 0; c < 4; ++c) {
      float rc = frcp(cnt[c]);
      float mean = s1[c] * rc;
      float ss = s2[c] - mean * s1[c];
      float delta = (1.0f - ss) * rc;
      tau[c] = mean - sqrtf(fmaxf(delta, 0.0f));
    }

    // weights -> Bs[t = 4g+c][pi = 8j + i]: one b128 write per t
#pragma unroll
    for (int c = 0; c < 4; ++c) {
      float u[8];
#pragma unroll
      for (int i = 0; i < 8; ++i) {
        float v = fmaxf(xv[i][c] - tau[c], 0.0f);
        u[i] = v * v;
      }
      uint4 w;
      w.x = pk2bf(u[0], u[1]);
      w.y = pk2bf(u[2], u[3]);
      w.z = pk2bf(u[4], u[5]);
      w.w = pk2bf(u[6], u[7]);
      *(uint4*)&Bs[(g * 4 + c) * BS_STRIDE + j * 8] = w;
    }
  }
  __syncthreads();  // Bs complete (only barrier in the kernel)

  // ---- 2. GEMM, one (chunk, sub) at a time; in-register transpose store ----
#pragma unroll
  for (int c = 0; c < 2; ++c) {
#pragma unroll
    for (int sub = 0; sub < 2; ++sub) {
      const int b = c * 128 + wid * 32 + sub * 16 + row16;  // this lane's output col
      const unsigned short* xptr = xb2 + ((size_t)m * B_ + b) * D_ + quad * 8;
      short8 xfr[4];
#pragma unroll
      for (int ks = 0; ks < 4; ++ks) xfr[ks] = *(const short8*)(xptr + ks * 32);

      floatx4 acc[4];
#pragma unroll
      for (int cf = 0; cf < 4; ++cf) acc[cf] = (floatx4){0.f, 0.f, 0.f, 0.f};
#pragma unroll
      for (int cf = 0; cf < 4; ++cf) {
        short8 afr[4];
#pragma unroll
        for (int ks = 0; ks < 4; ++ks)
          afr[ks] = *(const short8*)&Bs[(cf * 16 + row16) * BS_STRIDE + ks * 32 + quad * 8];
#pragma unroll
        for (int ks = 0; ks < 4; ++ks)
          acc[cf] = __builtin_amdgcn_mfma_f32_16x16x32_bf16(afr[ks], xfr[ks], acc[cf], 0, 0, 0);
      }

      // pack: X[cf] = bf16x4 for t in [cf*16 + quad*4, +4) at col b
      unsigned X0x = pk2bf(acc[0][0], acc[0][1]), X0y = pk2bf(acc[0][2], acc[0][3]);
      unsigned X1x = pk2bf(acc[1][0], acc[1][1]), X1y = pk2bf(acc[1][2], acc[1][3]);
      unsigned X2x = pk2bf(acc[2][0], acc[2][1]), X2y = pk2bf(acc[2][2], acc[2][3]);
      unsigned X3x = pk2bf(acc[3][0], acc[3][1]), X3y = pk2bf(acc[3][2], acc[3][3]);

      // 4x4 butterfly transpose across quads (col preserved):
      // stage 1: quad bit1 <-> slot bit1 (lane xor 32)
      const bool hi2 = (quad & 2) != 0;
      unsigned s0x = hi2 ? X0x : X2x, s0y = hi2 ? X0y : X2y;
      unsigned s1x = hi2 ? X1x : X3x, s1y = hi2 ? X1y : X3y;
      unsigned r0x = __shfl_xor(s0x, 32), r0y = __shfl_xor(s0y, 32);
      unsigned r1x = __shfl_xor(s1x, 32), r1y = __shfl_xor(s1y, 32);
      unsigned A0x = hi2 ? r0x : X0x, A0y = hi2 ? r0y : X0y;
      unsigned A1x = hi2 ? r1x : X1x, A1y = hi2 ? r1y : X1y;
      unsigned A2x = hi2 ? X2x : r0x, A2y = hi2 ? X2y : r0y;
      unsigned A3x = hi2 ? X3x : r1x, A3y = hi2 ? X3y : r1y;
      // stage 2: quad bit0 <-> slot bit0 (lane xor 16)
      const bool odd = (quad & 1) != 0;
      unsigned t0x = odd ? A0x : A1x, t0y = odd ? A0y : A1y;
      unsigned t1x = odd ? A2x : A3x, t1y = odd ? A2y : A3y;
      unsigned u0x = __shfl_xor(t0x, 16), u0y = __shfl_xor(t0y, 16);
      unsigned u1x = __shfl_xor(t1x, 16), u1y = __shfl_xor(t1y, 16);
      uint4 w0, w1;
      w0.x = odd ? u0x : A0x;  w0.y = odd ? u0y : A0y;
      w0.z = odd ? A1x : u0x;  w0.w = odd ? A1y : u0y;
      w1.x = odd ? u1x : A2x;  w1.y = odd ? u1y : A2y;
      w1.z = odd ? A3x : u1x;  w1.w = odd ? A3y : u1y;

      // 32B per lane; quads 0..3 of a column cover 128B contiguous t-range
      unsigned short* dst = priors + (((size_t)n * B_ + b) * M_ + m) * T_ + quad * 16;
      *(uint4*)dst = w0;
      *(uint4*)(dst + 8) = w1;
    }
  }
}

// ---------------------------------------------------------------------------
// K2 (R19): R17 body unchanged; __launch_bounds__(256, 8) — the one change
// this round. Grid is 2048 blocks = exactly 8/CU; VGPR already 64 (the
// 8-waves/SIMD boundary), LDS 1KB. (256,4) was capping residency at half
// for no reason. More resident waves hide the sigmoid/exp + MFMA chains.
// ---------------------------------------------------------------------------
__global__ __launch_bounds__(256, 8) void k_route(const unsigned short* __restrict__ priors,
                                                  const unsigned short* __restrict__ lhn,
                                                  const float* __restrict__ thrT,
                                                  const float* __restrict__ gamma,
                                                  const float* __restrict__ beta,
                                                  float* __restrict__ out) {
  const int n = blockIdx.x, g4 = blockIdx.y;
  const int tid = threadIdx.x;
  const int wid = tid >> 6, lane = tid & 63;
  const int col = lane & 15, quad = lane >> 4;

  __shared__ float probL[4][64];

  const int b = g4 * 4 + wid;  // wave's batch element

  const unsigned short* base = priors + ((size_t)n * B_ + b) * (M_ * T_);  // 8KB contiguous
  short8 afr[4][2];  // A[m = mt*16+col][k(t) = ks*32+quad*8+j]
#pragma unroll
  for (int mt = 0; mt < 4; ++mt)
#pragma unroll
    for (int ks = 0; ks < 2; ++ks)
      afr[mt][ks] = *(const short8*)(base + (mt * 16 + col) * T_ + ks * 32 + quad * 8);

  float thv = thrT[n * 64 + lane];

  float dis[4][4];
#pragma unroll
  for (int mt = 0; mt < 4; ++mt)
#pragma unroll
    for (int r = 0; r < 4; ++r) dis[mt][r] = 0.f;

#pragma unroll
  for (int s4 = 0; s4 < 4; ++s4) {
    floatx4 acc[4][2];
#pragma unroll
    for (int mt = 0; mt < 4; ++mt)
#pragma unroll
      for (int lt = 0; lt < 2; ++lt) acc[mt][lt] = (floatx4){0.f, 0.f, 0.f, 0.f};

#pragma unroll
    for (int lt = 0; lt < 2; ++lt) {
#pragma unroll
      for (int ks = 0; ks < 2; ++ks) {
        short8 bfr = *(const short8*)(lhn + (s4 * 32 + lt * 16 + col) * T_ + ks * 32 + quad * 8);
#pragma unroll
        for (int mt = 0; mt < 4; ++mt)
          acc[mt][lt] = __builtin_amdgcn_mfma_f32_16x16x32_bf16(afr[mt][ks], bfr, acc[mt][lt], 0, 0, 0);
      }
    }

#pragma unroll
    for (int mt = 0; mt < 4; ++mt)
#pragma unroll
      for (int lt = 0; lt < 2; ++lt)
#pragma unroll
        for (int r = 0; r < 4; ++r)
          acc[mt][lt][r] = frcp(1.0f + __expf(-acc[mt][lt][r]));

    float mc[2];
#pragma unroll
    for (int lt = 0; lt < 2; ++lt) {
      float s = 0.f;
#pragma unroll
      for (int mt = 0; mt < 4; ++mt)
#pragma unroll
        for (int r = 0; r < 4; ++r) s += acc[mt][lt][r];
      s += __shfl_xor(s, 16);
      s += __shfl_xor(s, 32);
      mc[lt] = s * (1.0f / 64.0f);
    }

#pragma unroll
    for (int mt = 0; mt < 4; ++mt)
#pragma unroll
      for (int r = 0; r < 4; ++r) {
        float s = 0.f;
#pragma unroll
        for (int lt = 0; lt < 2; ++lt) {
          float df = acc[mt][lt][r] - mc[lt];
          s = fmaf(df, df, s);
        }
        dis[mt][r] += s;
      }
  }

  // dis: reduce over col (16-lane rows) — DPP ladder
#pragma unroll
  for (int mt = 0; mt < 4; ++mt)
#pragma unroll
    for (int r = 0; r < 4; ++r) dis[mt][r] = rsum16(dis[mt][r]);

  float e[4][4];
  float mxw = 0.f;
#pragma unroll
  for (int mt = 0; mt < 4; ++mt)
#pragma unroll
    for (int r = 0; r < 4; ++r) {
      float th = __shfl(thv, mt * 16 + quad * 4 + r);
      float w = fmaxf(th * th - dis[mt][r] * (1.0f / 128.0f), 0.0f);
      e[mt][r] = w;
      mxw = fmaxf(mxw, w);
    }
  mxw = fmaxf(mxw, __shfl_xor(mxw, 16));
  mxw = fmaxf(mxw, __shfl_xor(mxw, 32));
  float ssum = 0.f;
#pragma unroll
  for (int mt = 0; mt < 4; ++mt)
#pragma unroll
    for (int r = 0; r < 4; ++r) {
      e[mt][r] = __expf(e[mt][r] - mxw);
      ssum += e[mt][r];
    }
  ssum += __shfl_xor(ssum, 16);
  ssum += __shfl_xor(ssum, 32);
  float inv = frcp(ssum);
  if (col == 0) {
#pragma unroll
    for (int mt = 0; mt < 4; ++mt)
#pragma unroll
      for (int r = 0; r < 4; ++r)
        probL[wid][mt * 16 + quad * 4 + r] = e[mt][r] * inv;
  }
  // same-wave LDS write->read: compiler inserts lgkmcnt wait (no barrier)

  float pr[4];
#pragma unroll
  for (int mt = 0; mt < 4; ++mt) pr[mt] = probL[wid][mt * 16 + col];

  float o[2][8];
#pragma unroll
  for (int ks = 0; ks < 2; ++ks)
#pragma unroll
    for (int j = 0; j < 8; ++j) o[ks][j] = 0.f;
#pragma unroll
  for (int mt = 0; mt < 4; ++mt)
#pragma unroll
    for (int ks = 0; ks < 2; ++ks)
#pragma unroll
      for (int j = 0; j < 8; ++j)
        o[ks][j] = fmaf(pr[mt], bf2f((unsigned short)afr[mt][ks][j]), o[ks][j]);
  // o: reduce over col (16-lane rows) — DPP ladder
#pragma unroll
  for (int ks = 0; ks < 2; ++ks)
#pragma unroll
    for (int j = 0; j < 8; ++j) o[ks][j] = rsum16(o[ks][j]);

  float mu = 0.f;
#pragma unroll
  for (int ks = 0; ks < 2; ++ks)
#pragma unroll
    for (int j = 0; j < 8; ++j) mu += o[ks][j];
  mu += __shfl_xor(mu, 16);
  mu += __shfl_xor(mu, 32);
  mu *= (1.0f / 64.0f);
  float var = 0.f;
#pragma unroll
  for (int ks = 0; ks < 2; ++ks)
#pragma unroll
    for (int j = 0; j < 8; ++j) {
      float d = o[ks][j] - mu;
      o[ks][j] = d;
      var = fmaf(d, d, var);
    }
  var += __shfl_xor(var, 16);
  var += __shfl_xor(var, 32);
  var *= (1.0f / 64.0f);
  float rstd = rsqrtf(var + 1e-5f);

  if (col == 0) {
    float* obase = out + ((size_t)b * N_ + n) * T_;
#pragma unroll
    for (int ks = 0; ks < 2; ++ks) {
      int tb = ks * 32 + quad * 8;
      float4 g0 = *(const float4*)(gamma + tb);
      float4 g1 = *(const float4*)(gamma + tb + 4);
      float4 b0 = *(const float4*)(beta + tb);
      float4 b1 = *(const float4*)(beta + tb + 4);
      float4 r0, r1;
      r0.x = o[ks][0] * rstd * g0.x + b0.x;
      r0.y = o[ks][1] * rstd * g0.y + b0.y;
      r0.z = o[ks][2] * rstd * g0.z + b0.z;
      r0.w = o[ks][3] * rstd * g0.w + b0.w;
      r1.x = o[ks][4] * rstd * g1.x + b1.x;
      r1.y = o[ks][5] * rstd * g1.y + b1.y;
      r1.z = o[ks][6] * rstd * g1.z + b1.z;
      r1.w = o[ks][7] * rstd * g1.w + b1.w;
      *(float4*)(obase + tb) = r0;
      *(float4*)(obase + tb + 4) = r1;
    }
  }
}

// ---------------------------------------------------------------------------
// Workspace layout (bytes):
//   priors [N][B][M][T]   bf16 : off 0,          67,108,864
//   xb2    [M][B][pi(D)]  bf16 : off 67,108,864,  4,194,304
//   LHn    [L][T]         bf16 : off 71,303,168,     16,384
//   thrT   [N][M]         fp32 : off 71,319,552,      8,192
// ---------------------------------------------------------------------------
extern "C" void kernel_launch(void* const* d_in, const int* in_sizes, int n_in,
                              void* d_out, int out_size, void* d_ws, size_t ws_size,
                              hipStream_t stream) {
  const float* x = (const float*)d_in[0];
  const float* rw = (const float*)d_in[1];
  const float* thr = (const float*)d_in[2];
  const float* leaves = (const float*)d_in[3];
  const float* gamma = (const float*)d_in[4];
  const float* beta = (const float*)d_in[5];
  float* out = (float*)d_out;

  char* ws = (char*)d_ws;
  unsigned short* priors = (unsigned short*)(ws);
  unsigned short* xb2 = (unsigned short*)(ws + 67108864);
  unsigned short* lhn = (unsigned short*)(ws + 71303168);
  float* thrT = (float*)(ws + 71319552);

  hipLaunchKernelGGL(k_prep, dim3(1026), dim3(256), 0, stream, x, leaves, xb2, lhn, thr, thrT);
  hipLaunchKernelGGL(k_wpriors, dim3(64, 32), dim3(256), 0, stream, xb2, rw, priors);
  hipLaunchKernelGGL(k_route, dim3(32, 64), dim3(256), 0, stream, priors, lhn, thrT, gamma, beta, out);
}

// Round 5
// 173.297 us; speedup vs baseline: 1.4353x; 1.4353x over previous
//
#include <hip/hip_runtime.h>
#include <hip/hip_bf16.h>
#include <math.h>

// Problem sizes (fixed by reference): B=256, M=64, N=32, D=128, T=64, L=128
#define B_ 256
#define M_ 64
#define N_ 32
#define D_ 128
#define T_ 64
#define L_ 128

typedef __attribute__((ext_vector_type(8))) short short8;   // 8 bf16 = 4 VGPRs (MFMA A/B frag)
typedef __attribute__((ext_vector_type(4))) float floatx4;  // MFMA C/D frag

__device__ __forceinline__ unsigned short f2bf(float f) {
  unsigned int u = __float_as_uint(f);
  unsigned int r = (u + 0x7fffu + ((u >> 16) & 1u)) >> 16;  // RNE
  return (unsigned short)r;
}
__device__ __forceinline__ float bf2f(unsigned short s) {
  return __uint_as_float(((unsigned int)s) << 16);
}
__device__ __forceinline__ float frcp(float x) { return __builtin_amdgcn_rcpf(x); }
// packed 2x f32 -> bf16x2 (low = a, high = b); lowers to HW packed cvt on gfx950
__device__ __forceinline__ unsigned pk2bf(float a, float b) {
  __hip_bfloat162 h = __float22bfloat162_rn(make_float2(a, b));
  unsigned u;
  __builtin_memcpy(&u, &h, 4);
  return u;
}

// ---------------------------------------------------------------------------
// DPP 16-lane reductions (lane bits 0-3 == DPP row). row_ror:{1,2,4,8} chain
// gives every lane the full 16-lane result at VALU rate — replaces the
// ds_bpermute ladders __shfl_xor(x, 1/2/4/8) would emit (~40cy each, LDS pipe).
// ---------------------------------------------------------------------------
template <int CTRL>
__device__ __forceinline__ float dpp_f(float x) {
  return __int_as_float(__builtin_amdgcn_update_dpp(
      __float_as_int(x), __float_as_int(x), CTRL, 0xf, 0xf, false));
}
__device__ __forceinline__ float rsum16(float x) {
  x += dpp_f<0x121>(x);  // row_ror:1
  x += dpp_f<0x122>(x);  // row_ror:2
  x += dpp_f<0x124>(x);  // row_ror:4
  x += dpp_f<0x128>(x);  // row_ror:8
  return x;
}
__device__ __forceinline__ float rmax16(float x) {
  x = fmaxf(x, dpp_f<0x121>(x));
  x = fmaxf(x, dpp_f<0x122>(x));
  x = fmaxf(x, dpp_f<0x124>(x));
  x = fmaxf(x, dpp_f<0x128>(x));
  return x;
}

// ---------------------------------------------------------------------------
// K0 (R20): blocks < 1024: x -> bf16 PI-PERMUTED xb2[m][b][pi(d)],
// pi(16i+j) = 8j+i. block 1024: leaves norm — NOW PARALLEL: 2 threads/row,
// 8 independent float4 loads each (was: 128 threads x 64-iter serial scalar
// loop = ~64 dependent HBM round-trips tail-extending the dispatch).
// block 1025: thrT.
// ---------------------------------------------------------------------------
__global__ __launch_bounds__(256) void k_prep(const float* __restrict__ x,
                                              const float* __restrict__ leaves,
                                              unsigned short* __restrict__ xb2,
                                              unsigned short* __restrict__ lhn,
                                              const float* __restrict__ thr,
                                              float* __restrict__ thrT) {
  const int tid = threadIdx.x;
  const int bx = blockIdx.x;
  if (bx < 1024) {
    int idx = bx * 256 + tid;          // (m, b, j)
    int j = idx & 15, b = (idx >> 4) & 255, m = idx >> 12;
    const float* xs = x + ((size_t)b * M_ + m) * D_ + j;   // d = 16i + j
    float v[8];
#pragma unroll
    for (int i = 0; i < 8; ++i) v[i] = xs[i * 16];
    unsigned short* dst = xb2 + ((size_t)m * B_ + b) * D_ + j * 8;  // pi pos 8j+i
    uint4 w;
    w.x = pk2bf(v[0], v[1]);
    w.y = pk2bf(v[2], v[3]);
    w.z = pk2bf(v[4], v[5]);
    w.w = pk2bf(v[6], v[7]);
    *(uint4*)dst = w;
  } else if (bx == 1024) {
    // leaves norm: row = tid>>1, half = tid&1 -> 32 contiguous floats each
    const int row = tid >> 1, half = tid & 1;
    const float* r = leaves + row * T_ + half * 32;
    float4 v[8];
#pragma unroll
    for (int i = 0; i < 8; ++i) v[i] = *(const float4*)(r + i * 4);
    float ss = 0.f;
#pragma unroll
    for (int i = 0; i < 8; ++i) {
      ss = fmaf(v[i].x, v[i].x, ss);
      ss = fmaf(v[i].y, v[i].y, ss);
      ss = fmaf(v[i].z, v[i].z, ss);
      ss = fmaf(v[i].w, v[i].w, ss);
    }
    ss += __shfl_xor(ss, 1);  // partner thread holds the other half of the row
    float inv = frcp(fmaxf(sqrtf(ss), 1e-12f));
    unsigned short* o = lhn + row * T_ + half * 32;
#pragma unroll
    for (int i = 0; i < 4; ++i) {
      uint4 w;
      w.x = pk2bf(v[2 * i].x * inv, v[2 * i].y * inv);
      w.y = pk2bf(v[2 * i].z * inv, v[2 * i].w * inv);
      w.z = pk2bf(v[2 * i + 1].x * inv, v[2 * i + 1].y * inv);
      w.w = pk2bf(v[2 * i + 1].z * inv, v[2 * i + 1].w * inv);
      *(uint4*)(o + i * 8) = w;
    }
  } else {  // thrT[n][m] = thr[m][n]
#pragma unroll
    for (int k = 0; k < 8; ++k) {
      int idx = k * 256 + tid;
      int nn = idx >> 6, mm = idx & 63;
      thrT[idx] = thr[mm * N_ + nn];
    }
  }
}

// ---------------------------------------------------------------------------
// K1 (R17 verbatim, verified 47.6us): no Ct buffer, register butterfly
// transpose, 8 blocks/CU, DPP reductions in entmax.
// ---------------------------------------------------------------------------
#define BS_STRIDE 136
__global__ __launch_bounds__(256, 8) void k_wpriors(const unsigned short* __restrict__ xb2,
                                                    const float* __restrict__ rw,
                                                    unsigned short* __restrict__ priors) {
  const int m = blockIdx.x, n = blockIdx.y;
  const int tid = threadIdx.x;
  const int wid = tid >> 6, lane = tid & 63;
  const int row16 = lane & 15, quad = lane >> 4;

  __shared__ __align__(16) unsigned short Bs[64 * BS_STRIDE];  // W [t][pi_k] bf16

  // ---- 1. entmax (direct-global float4-along-T) ----
  {
    const int g = tid >> 4, j = tid & 15;
    const float* base = rw + (size_t)(m * N_ + n) * (D_ * T_) + g * 4;
    floatx4 xv[8];
#pragma unroll
    for (int i = 0; i < 8; ++i)
      xv[i] = *(const floatx4*)(base + (size_t)(i * 16 + j) * T_);

    floatx4 mx = xv[0];
#pragma unroll
    for (int i = 1; i < 8; ++i)
#pragma unroll
      for (int c = 0; c < 4; ++c) mx[c] = fmaxf(mx[c], xv[i][c]);
#pragma unroll
    for (int c = 0; c < 4; ++c) mx[c] = rmax16(mx[c]);
#pragma unroll
    for (int i = 0; i < 8; ++i)
#pragma unroll
      for (int c = 0; c < 4; ++c) xv[i][c] = (xv[i][c] - mx[c]) * 0.5f;

    floatx4 lo = (floatx4){-1.f, -1.f, -1.f, -1.f};
    floatx4 hi = (floatx4){0.f, 0.f, 0.f, 0.f};
    for (int it = 0; it < 8; ++it) {
      floatx4 tau, f = (floatx4){0.f, 0.f, 0.f, 0.f};
#pragma unroll
      for (int c = 0; c < 4; ++c) tau[c] = 0.5f * (lo[c] + hi[c]);
#pragma unroll
      for (int i = 0; i < 8; ++i)
#pragma unroll
        for (int c = 0; c < 4; ++c) {
          float u = fmaxf(xv[i][c] - tau[c], 0.0f);
          f[c] = fmaf(u, u, f[c]);
        }
#pragma unroll
      for (int c = 0; c < 4; ++c) f[c] = rsum16(f[c]);
#pragma unroll
      for (int c = 0; c < 4; ++c) {
        bool ge = f[c] >= 1.0f;
        lo[c] = ge ? tau[c] : lo[c];
        hi[c] = ge ? hi[c] : tau[c];
      }
    }
    floatx4 tau0, cnt = (floatx4){0,0,0,0}, s1 = (floatx4){0,0,0,0}, s2 = (floatx4){0,0,0,0};
#pragma unroll
    for (int c = 0; c < 4; ++c) tau0[c] = 0.5f * (lo[c] + hi[c]);
#pragma unroll
    for (int i = 0; i < 8; ++i)
#pragma unroll
      for (int c = 0; c < 4; ++c) {
        bool in = xv[i][c] > tau0[c];
        float q = in ? xv[i][c] : 0.0f;
        cnt[c] += in ? 1.0f : 0.0f;
        s1[c] += q;
        s2[c] = fmaf(q, q, s2[c]);
      }
#pragma unroll
    for (int c = 0; c < 4; ++c) {
      cnt[c] = rsum16(cnt[c]);
      s1[c] = rsum16(s1[c]);
      s2[c] = rsum16(s2[c]);
    }
    floatx4 tau;
#pragma unroll
    for (int c = 0; c < 4; ++c) {
      float rc = frcp(cnt[c]);
      float mean = s1[c] * rc;
      float ss = s2[c] - mean * s1[c];
      float delta = (1.0f - ss) * rc;
      tau[c] = mean - sqrtf(fmaxf(delta, 0.0f));
    }

    // weights -> Bs[t = 4g+c][pi = 8j + i]: one b128 write per t
#pragma unroll
    for (int c = 0; c < 4; ++c) {
      float u[8];
#pragma unroll
      for (int i = 0; i < 8; ++i) {
        float v = fmaxf(xv[i][c] - tau[c], 0.0f);
        u[i] = v * v;
      }
      uint4 w;
      w.x = pk2bf(u[0], u[1]);
      w.y = pk2bf(u[2], u[3]);
      w.z = pk2bf(u[4], u[5]);
      w.w = pk2bf(u[6], u[7]);
      *(uint4*)&Bs[(g * 4 + c) * BS_STRIDE + j * 8] = w;
    }
  }
  __syncthreads();  // Bs complete (only barrier in the kernel)

  // ---- 2. GEMM, one (chunk, sub) at a time; in-register transpose store ----
#pragma unroll
  for (int c = 0; c < 2; ++c) {
#pragma unroll
    for (int sub = 0; sub < 2; ++sub) {
      const int b = c * 128 + wid * 32 + sub * 16 + row16;  // this lane's output col
      const unsigned short* xptr = xb2 + ((size_t)m * B_ + b) * D_ + quad * 8;
      short8 xfr[4];
#pragma unroll
      for (int ks = 0; ks < 4; ++ks) xfr[ks] = *(const short8*)(xptr + ks * 32);

      floatx4 acc[4];
#pragma unroll
      for (int cf = 0; cf < 4; ++cf) acc[cf] = (floatx4){0.f, 0.f, 0.f, 0.f};
#pragma unroll
      for (int cf = 0; cf < 4; ++cf) {
        short8 afr[4];
#pragma unroll
        for (int ks = 0; ks < 4; ++ks)
          afr[ks] = *(const short8*)&Bs[(cf * 16 + row16) * BS_STRIDE + ks * 32 + quad * 8];
#pragma unroll
        for (int ks = 0; ks < 4; ++ks)
          acc[cf] = __builtin_amdgcn_mfma_f32_16x16x32_bf16(afr[ks], xfr[ks], acc[cf], 0, 0, 0);
      }

      // pack: X[cf] = bf16x4 for t in [cf*16 + quad*4, +4) at col b
      unsigned X0x = pk2bf(acc[0][0], acc[0][1]), X0y = pk2bf(acc[0][2], acc[0][3]);
      unsigned X1x = pk2bf(acc[1][0], acc[1][1]), X1y = pk2bf(acc[1][2], acc[1][3]);
      unsigned X2x = pk2bf(acc[2][0], acc[2][1]), X2y = pk2bf(acc[2][2], acc[2][3]);
      unsigned X3x = pk2bf(acc[3][0], acc[3][1]), X3y = pk2bf(acc[3][2], acc[3][3]);

      // 4x4 butterfly transpose across quads (col preserved):
      // stage 1: quad bit1 <-> slot bit1 (lane xor 32)
      const bool hi2 = (quad & 2) != 0;
      unsigned s0x = hi2 ? X0x : X2x, s0y = hi2 ? X0y : X2y;
      unsigned s1x = hi2 ? X1x : X3x, s1y = hi2 ? X1y : X3y;
      unsigned r0x = __shfl_xor(s0x, 32), r0y = __shfl_xor(s0y, 32);
      unsigned r1x = __shfl_xor(s1x, 32), r1y = __shfl_xor(s1y, 32);
      unsigned A0x = hi2 ? r0x : X0x, A0y = hi2 ? r0y : X0y;
      unsigned A1x = hi2 ? r1x : X1x, A1y = hi2 ? r1y : X1y;
      unsigned A2x = hi2 ? X2x : r0x, A2y = hi2 ? X2y : r0y;
      unsigned A3x = hi2 ? X3x : r1x, A3y = hi2 ? X3y : r1y;
      // stage 2: quad bit0 <-> slot bit0 (lane xor 16)
      const bool odd = (quad & 1) != 0;
      unsigned t0x = odd ? A0x : A1x, t0y = odd ? A0y : A1y;
      unsigned t1x = odd ? A2x : A3x, t1y = odd ? A2y : A3y;
      unsigned u0x = __shfl_xor(t0x, 16), u0y = __shfl_xor(t0y, 16);
      unsigned u1x = __shfl_xor(t1x, 16), u1y = __shfl_xor(t1y, 16);
      uint4 w0, w1;
      w0.x = odd ? u0x : A0x;  w0.y = odd ? u0y : A0y;
      w0.z = odd ? A1x : u0x;  w0.w = odd ? A1y : u0y;
      w1.x = odd ? u1x : A2x;  w1.y = odd ? u1y : A2y;
      w1.z = odd ? A3x : u1x;  w1.w = odd ? A3y : u1y;

      // 32B per lane; quads 0..3 of a column cover 128B contiguous t-range
      unsigned short* dst = priors + (((size_t)n * B_ + b) * M_ + m) * T_ + quad * 16;
      *(uint4*)dst = w0;
      *(uint4*)(dst + 8) = w1;
    }
  }
}

// ---------------------------------------------------------------------------
// K2 (R20 = R17 verbatim): block = (n, g4); wave owns ONE b; DPP reductions;
// __launch_bounds__(256, 4). R19 PROVED (256,8) forces the ~90-VGPR live set
// (afr 32 + acc 32 + dis 16 + misc) to spill: FETCH 33->216MB, dur 2x.
// 64 VGPR at (256,4) does NOT spill (WRITE_SIZE == 2MB == outputs exactly).
// Do not touch the launch bounds here again.
// ---------------------------------------------------------------------------
__global__ __launch_bounds__(256, 4) void k_route(const unsigned short* __restrict__ priors,
                                                  const unsigned short* __restrict__ lhn,
                                                  const float* __restrict__ thrT,
                                                  const float* __restrict__ gamma,
                                                  const float* __restrict__ beta,
                                                  float* __restrict__ out) {
  const int n = blockIdx.x, g4 = blockIdx.y;
  const int tid = threadIdx.x;
  const int wid = tid >> 6, lane = tid & 63;
  const int col = lane & 15, quad = lane >> 4;

  __shared__ float probL[4][64];

  const int b = g4 * 4 + wid;  // wave's batch element

  const unsigned short* base = priors + ((size_t)n * B_ + b) * (M_ * T_);  // 8KB contiguous
  short8 afr[4][2];  // A[m = mt*16+col][k(t) = ks*32+quad*8+j]
#pragma unroll
  for (int mt = 0; mt < 4; ++mt)
#pragma unroll
    for (int ks = 0; ks < 2; ++ks)
      afr[mt][ks] = *(const short8*)(base + (mt * 16 + col) * T_ + ks * 32 + quad * 8);

  float thv = thrT[n * 64 + lane];

  float dis[4][4];
#pragma unroll
  for (int mt = 0; mt < 4; ++mt)
#pragma unroll
    for (int r = 0; r < 4; ++r) dis[mt][r] = 0.f;

#pragma unroll
  for (int s4 = 0; s4 < 4; ++s4) {
    floatx4 acc[4][2];
#pragma unroll
    for (int mt = 0; mt < 4; ++mt)
#pragma unroll
      for (int lt = 0; lt < 2; ++lt) acc[mt][lt] = (floatx4){0.f, 0.f, 0.f, 0.f};

#pragma unroll
    for (int lt = 0; lt < 2; ++lt) {
#pragma unroll
      for (int ks = 0; ks < 2; ++ks) {
        short8 bfr = *(const short8*)(lhn + (s4 * 32 + lt * 16 + col) * T_ + ks * 32 + quad * 8);
#pragma unroll
        for (int mt = 0; mt < 4; ++mt)
          acc[mt][lt] = __builtin_amdgcn_mfma_f32_16x16x32_bf16(afr[mt][ks], bfr, acc[mt][lt], 0, 0, 0);
      }
    }

#pragma unroll
    for (int mt = 0; mt < 4; ++mt)
#pragma unroll
      for (int lt = 0; lt < 2; ++lt)
#pragma unroll
        for (int r = 0; r < 4; ++r)
          acc[mt][lt][r] = frcp(1.0f + __expf(-acc[mt][lt][r]));

    float mc[2];
#pragma unroll
    for (int lt = 0; lt < 2; ++lt) {
      float s = 0.f;
#pragma unroll
      for (int mt = 0; mt < 4; ++mt)
#pragma unroll
        for (int r = 0; r < 4; ++r) s += acc[mt][lt][r];
      s += __shfl_xor(s, 16);
      s += __shfl_xor(s, 32);
      mc[lt] = s * (1.0f / 64.0f);
    }

#pragma unroll
    for (int mt = 0; mt < 4; ++mt)
#pragma unroll
      for (int r = 0; r < 4; ++r) {
        float s = 0.f;
#pragma unroll
        for (int lt = 0; lt < 2; ++lt) {
          float df = acc[mt][lt][r] - mc[lt];
          s = fmaf(df, df, s);
        }
        dis[mt][r] += s;
      }
  }

  // dis: reduce over col (16-lane rows) — DPP ladder
#pragma unroll
  for (int mt = 0; mt < 4; ++mt)
#pragma unroll
    for (int r = 0; r < 4; ++r) dis[mt][r] = rsum16(dis[mt][r]);

  float e[4][4];
  float mxw = 0.f;
#pragma unroll
  for (int mt = 0; mt < 4; ++mt)
#pragma unroll
    for (int r = 0; r < 4; ++r) {
      float th = __shfl(thv, mt * 16 + quad * 4 + r);
      float w = fmaxf(th * th - dis[mt][r] * (1.0f / 128.0f), 0.0f);
      e[mt][r] = w;
      mxw = fmaxf(mxw, w);
    }
  mxw = fmaxf(mxw, __shfl_xor(mxw, 16));
  mxw = fmaxf(mxw, __shfl_xor(mxw, 32));
  float ssum = 0.f;
#pragma unroll
  for (int mt = 0; mt < 4; ++mt)
#pragma unroll
    for (int r = 0; r < 4; ++r) {
      e[mt][r] = __expf(e[mt][r] - mxw);
      ssum += e[mt][r];
    }
  ssum += __shfl_xor(ssum, 16);
  ssum += __shfl_xor(ssum, 32);
  float inv = frcp(ssum);
  if (col == 0) {
#pragma unroll
    for (int mt = 0; mt < 4; ++mt)
#pragma unroll
      for (int r = 0; r < 4; ++r)
        probL[wid][mt * 16 + quad * 4 + r] = e[mt][r] * inv;
  }
  // same-wave LDS write->read: compiler inserts lgkmcnt wait (no barrier)

  float pr[4];
#pragma unroll
  for (int mt = 0; mt < 4; ++mt) pr[mt] = probL[wid][mt * 16 + col];

  float o[2][8];
#pragma unroll
  for (int ks = 0; ks < 2; ++ks)
#pragma unroll
    for (int j = 0; j < 8; ++j) o[ks][j] = 0.f;
#pragma unroll
  for (int mt = 0; mt < 4; ++mt)
#pragma unroll
    for (int ks = 0; ks < 2; ++ks)
#pragma unroll
      for (int j = 0; j < 8; ++j)
        o[ks][j] = fmaf(pr[mt], bf2f((unsigned short)afr[mt][ks][j]), o[ks][j]);
  // o: reduce over col (16-lane rows) — DPP ladder
#pragma unroll
  for (int ks = 0; ks < 2; ++ks)
#pragma unroll
    for (int j = 0; j < 8; ++j) o[ks][j] = rsum16(o[ks][j]);

  float mu = 0.f;
#pragma unroll
  for (int ks = 0; ks < 2; ++ks)
#pragma unroll
    for (int j = 0; j < 8; ++j) mu += o[ks][j];
  mu += __shfl_xor(mu, 16);
  mu += __shfl_xor(mu, 32);
  mu *= (1.0f / 64.0f);
  float var = 0.f;
#pragma unroll
  for (int ks = 0; ks < 2; ++ks)
#pragma unroll
    for (int j = 0; j < 8; ++j) {
      float d = o[ks][j] - mu;
      o[ks][j] = d;
      var = fmaf(d, d, var);
    }
  var += __shfl_xor(var, 16);
  var += __shfl_xor(var, 32);
  var *= (1.0f / 64.0f);
  float rstd = rsqrtf(var + 1e-5f);

  if (col == 0) {
    float* obase = out + ((size_t)b * N_ + n) * T_;
#pragma unroll
    for (int ks = 0; ks < 2; ++ks) {
      int tb = ks * 32 + quad * 8;
      float4 g0 = *(const float4*)(gamma + tb);
      float4 g1 = *(const float4*)(gamma + tb + 4);
      float4 b0 = *(const float4*)(beta + tb);
      float4 b1 = *(const float4*)(beta + tb + 4);
      float4 r0, r1;
      r0.x = o[ks][0] * rstd * g0.x + b0.x;
      r0.y = o[ks][1] * rstd * g0.y + b0.y;
      r0.z = o[ks][2] * rstd * g0.z + b0.z;
      r0.w = o[ks][3] * rstd * g0.w + b0.w;
      r1.x = o[ks][4] * rstd * g1.x + b1.x;
      r1.y = o[ks][5] * rstd * g1.y + b1.y;
      r1.z = o[ks][6] * rstd * g1.z + b1.z;
      r1.w = o[ks][7] * rstd * g1.w + b1.w;
      *(float4*)(obase + tb) = r0;
      *(float4*)(obase + tb + 4) = r1;
    }
  }
}

// ---------------------------------------------------------------------------
// Workspace layout (bytes):
//   priors [N][B][M][T]   bf16 : off 0,          67,108,864
//   xb2    [M][B][pi(D)]  bf16 : off 67,108,864,  4,194,304
//   LHn    [L][T]         bf16 : off 71,303,168,     16,384
//   thrT   [N][M]         fp32 : off 71,319,552,      8,192
// ---------------------------------------------------------------------------
extern "C" void kernel_launch(void* const* d_in, const int* in_sizes, int n_in,
                              void* d_out, int out_size, void* d_ws, size_t ws_size,
                              hipStream_t stream) {
  const float* x = (const float*)d_in[0];
  const float* rw = (const float*)d_in[1];
  const float* thr = (const float*)d_in[2];
  const float* leaves = (const float*)d_in[3];
  const float* gamma = (const float*)d_in[4];
  const float* beta = (const float*)d_in[5];
  float* out = (float*)d_out;

  char* ws = (char*)d_ws;
  unsigned short* priors = (unsigned short*)(ws);
  unsigned short* xb2 = (unsigned short*)(ws + 67108864);
  unsigned short* lhn = (unsigned short*)(ws + 71303168);
  float* thrT = (float*)(ws + 71319552);

  hipLaunchKernelGGL(k_prep, dim3(1026), dim3(256), 0, stream, x, leaves, xb2, lhn, thr, thrT);
  hipLaunchKernelGGL(k_wpriors, dim3(64, 32), dim3(256), 0, stream, xb2, rw, priors);
  hipLaunchKernelGGL(k_route, dim3(32, 64), dim3(256), 0, stream, priors, lhn, thrT, gamma, beta, out);
}

// Round 6
// 167.028 us; speedup vs baseline: 1.4892x; 1.0375x over previous
//
#include <hip/hip_runtime.h>
#include <hip/hip_bf16.h>
#include <math.h>

// Problem sizes (fixed by reference): B=256, M=64, N=32, D=128, T=64, L=128
#define B_ 256
#define M_ 64
#define N_ 32
#define D_ 128
#define T_ 64
#define L_ 128

typedef __attribute__((ext_vector_type(8))) short short8;   // 8 bf16 = 4 VGPRs (MFMA A/B frag)
typedef __attribute__((ext_vector_type(4))) float floatx4;  // MFMA C/D frag

__device__ __forceinline__ unsigned short f2bf(float f) {
  unsigned int u = __float_as_uint(f);
  unsigned int r = (u + 0x7fffu + ((u >> 16) & 1u)) >> 16;  // RNE
  return (unsigned short)r;
}
__device__ __forceinline__ float bf2f(unsigned short s) {
  return __uint_as_float(((unsigned int)s) << 16);
}
__device__ __forceinline__ float frcp(float x) { return __builtin_amdgcn_rcpf(x); }
// packed 2x f32 -> bf16x2 (low = a, high = b); lowers to HW packed cvt on gfx950
__device__ __forceinline__ unsigned pk2bf(float a, float b) {
  __hip_bfloat162 h = __float22bfloat162_rn(make_float2(a, b));
  unsigned u;
  __builtin_memcpy(&u, &h, 4);
  return u;
}

// ---------------------------------------------------------------------------
// DPP 16-lane reductions (lane bits 0-3 == DPP row). row_ror:{1,2,4,8} chain
// gives every lane the full 16-lane result at VALU rate — replaces the
// ds_bpermute ladders __shfl_xor(x, 1/2/4/8) would emit (~40cy each, LDS pipe).
// ---------------------------------------------------------------------------
template <int CTRL>
__device__ __forceinline__ float dpp_f(float x) {
  return __int_as_float(__builtin_amdgcn_update_dpp(
      __float_as_int(x), __float_as_int(x), CTRL, 0xf, 0xf, false));
}
__device__ __forceinline__ float rsum16(float x) {
  x += dpp_f<0x121>(x);  // row_ror:1
  x += dpp_f<0x122>(x);  // row_ror:2
  x += dpp_f<0x124>(x);  // row_ror:4
  x += dpp_f<0x128>(x);  // row_ror:8
  return x;
}
__device__ __forceinline__ float rmax16(float x) {
  x = fmaxf(x, dpp_f<0x121>(x));
  x = fmaxf(x, dpp_f<0x122>(x));
  x = fmaxf(x, dpp_f<0x124>(x));
  x = fmaxf(x, dpp_f<0x128>(x));
  return x;
}

// ---------------------------------------------------------------------------
// K0 (R20): blocks < 1024: x -> bf16 PI-PERMUTED xb2[m][b][pi(d)],
// pi(16i+j) = 8j+i. block 1024: leaves norm (parallel, 2 threads/row).
// block 1025: thrT.
// ---------------------------------------------------------------------------
__global__ __launch_bounds__(256) void k_prep(const float* __restrict__ x,
                                              const float* __restrict__ leaves,
                                              unsigned short* __restrict__ xb2,
                                              unsigned short* __restrict__ lhn,
                                              const float* __restrict__ thr,
                                              float* __restrict__ thrT) {
  const int tid = threadIdx.x;
  const int bx = blockIdx.x;
  if (bx < 1024) {
    int idx = bx * 256 + tid;          // (m, b, j)
    int j = idx & 15, b = (idx >> 4) & 255, m = idx >> 12;
    const float* xs = x + ((size_t)b * M_ + m) * D_ + j;   // d = 16i + j
    float v[8];
#pragma unroll
    for (int i = 0; i < 8; ++i) v[i] = xs[i * 16];
    unsigned short* dst = xb2 + ((size_t)m * B_ + b) * D_ + j * 8;  // pi pos 8j+i
    uint4 w;
    w.x = pk2bf(v[0], v[1]);
    w.y = pk2bf(v[2], v[3]);
    w.z = pk2bf(v[4], v[5]);
    w.w = pk2bf(v[6], v[7]);
    *(uint4*)dst = w;
  } else if (bx == 1024) {
    // leaves norm: row = tid>>1, half = tid&1 -> 32 contiguous floats each
    const int row = tid >> 1, half = tid & 1;
    const float* r = leaves + row * T_ + half * 32;
    float4 v[8];
#pragma unroll
    for (int i = 0; i < 8; ++i) v[i] = *(const float4*)(r + i * 4);
    float ss = 0.f;
#pragma unroll
    for (int i = 0; i < 8; ++i) {
      ss = fmaf(v[i].x, v[i].x, ss);
      ss = fmaf(v[i].y, v[i].y, ss);
      ss = fmaf(v[i].z, v[i].z, ss);
      ss = fmaf(v[i].w, v[i].w, ss);
    }
    ss += __shfl_xor(ss, 1);  // partner thread holds the other half of the row
    float inv = frcp(fmaxf(sqrtf(ss), 1e-12f));
    unsigned short* o = lhn + row * T_ + half * 32;
#pragma unroll
    for (int i = 0; i < 4; ++i) {
      uint4 w;
      w.x = pk2bf(v[2 * i].x * inv, v[2 * i].y * inv);
      w.y = pk2bf(v[2 * i].z * inv, v[2 * i].w * inv);
      w.z = pk2bf(v[2 * i + 1].x * inv, v[2 * i + 1].y * inv);
      w.w = pk2bf(v[2 * i + 1].z * inv, v[2 * i + 1].w * inv);
      *(uint4*)(o + i * 8) = w;
    }
  } else {  // thrT[n][m] = thr[m][n]
#pragma unroll
    for (int k = 0; k < 8; ++k) {
      int idx = k * 256 + tid;
      int nn = idx >> 6, mm = idx & 63;
      thrT[idx] = thr[mm * N_ + nn];
    }
  }
}

// ---------------------------------------------------------------------------
// K1 (R21): R17 body verbatim; __launch_bounds__(256, 4) — the ONE change.
// Rationale: grid 2048 == capacity at 8 blocks/CU -> all blocks phase-locked
// (entmax VALU-phase chip-wide, then GEMM mem-phase chip-wide; VALUBusy 55%
// == exact serialized average). Capping residency at 4 blocks/CU makes the
// grid TWO passes deep: pass-2 blocks refill while pass-1 drains through the
// memory-bound GEMM, so pass-2 entmax (VALU) overlaps pass-1 GEMM (mem) via
// the HW scheduler — the overlap R18's in-wave weave failed to buy. Entmax
// still saturates VALU at 4 waves/SIMD (ILP 4 across c-components).
// ---------------------------------------------------------------------------
#define BS_STRIDE 136
__global__ __launch_bounds__(256, 4) void k_wpriors(const unsigned short* __restrict__ xb2,
                                                    const float* __restrict__ rw,
                                                    unsigned short* __restrict__ priors) {
  const int m = blockIdx.x, n = blockIdx.y;
  const int tid = threadIdx.x;
  const int wid = tid >> 6, lane = tid & 63;
  const int row16 = lane & 15, quad = lane >> 4;

  __shared__ __align__(16) unsigned short Bs[64 * BS_STRIDE];  // W [t][pi_k] bf16

  // ---- 1. entmax (direct-global float4-along-T) ----
  {
    const int g = tid >> 4, j = tid & 15;
    const float* base = rw + (size_t)(m * N_ + n) * (D_ * T_) + g * 4;
    floatx4 xv[8];
#pragma unroll
    for (int i = 0; i < 8; ++i)
      xv[i] = *(const floatx4*)(base + (size_t)(i * 16 + j) * T_);

    floatx4 mx = xv[0];
#pragma unroll
    for (int i = 1; i < 8; ++i)
#pragma unroll
      for (int c = 0; c < 4; ++c) mx[c] = fmaxf(mx[c], xv[i][c]);
#pragma unroll
    for (int c = 0; c < 4; ++c) mx[c] = rmax16(mx[c]);
#pragma unroll
    for (int i = 0; i < 8; ++i)
#pragma unroll
      for (int c = 0; c < 4; ++c) xv[i][c] = (xv[i][c] - mx[c]) * 0.5f;

    floatx4 lo = (floatx4){-1.f, -1.f, -1.f, -1.f};
    floatx4 hi = (floatx4){0.f, 0.f, 0.f, 0.f};
    for (int it = 0; it < 8; ++it) {
      floatx4 tau, f = (floatx4){0.f, 0.f, 0.f, 0.f};
#pragma unroll
      for (int c = 0; c < 4; ++c) tau[c] = 0.5f * (lo[c] + hi[c]);
#pragma unroll
      for (int i = 0; i < 8; ++i)
#pragma unroll
        for (int c = 0; c < 4; ++c) {
          float u = fmaxf(xv[i][c] - tau[c], 0.0f);
          f[c] = fmaf(u, u, f[c]);
        }
#pragma unroll
      for (int c = 0; c < 4; ++c) f[c] = rsum16(f[c]);
#pragma unroll
      for (int c = 0; c < 4; ++c) {
        bool ge = f[c] >= 1.0f;
        lo[c] = ge ? tau[c] : lo[c];
        hi[c] = ge ? hi[c] : tau[c];
      }
    }
    floatx4 tau0, cnt = (floatx4){0,0,0,0}, s1 = (floatx4){0,0,0,0}, s2 = (floatx4){0,0,0,0};
#pragma unroll
    for (int c = 0; c < 4; ++c) tau0[c] = 0.5f * (lo[c] + hi[c]);
#pragma unroll
    for (int i = 0; i < 8; ++i)
#pragma unroll
      for (int c = 0; c < 4; ++c) {
        bool in = xv[i][c] > tau0[c];
        float q = in ? xv[i][c] : 0.0f;
        cnt[c] += in ? 1.0f : 0.0f;
        s1[c] += q;
        s2[c] = fmaf(q, q, s2[c]);
      }
#pragma unroll
    for (int c = 0; c < 4; ++c) {
      cnt[c] = rsum16(cnt[c]);
      s1[c] = rsum16(s1[c]);
      s2[c] = rsum16(s2[c]);
    }
    floatx4 tau;
#pragma unroll
    for (int c = 0; c < 4; ++c) {
      float rc = frcp(cnt[c]);
      float mean = s1[c] * rc;
      float ss = s2[c] - mean * s1[c];
      float delta = (1.0f - ss) * rc;
      tau[c] = mean - sqrtf(fmaxf(delta, 0.0f));
    }

    // weights -> Bs[t = 4g+c][pi = 8j + i]: one b128 write per t
#pragma unroll
    for (int c = 0; c < 4; ++c) {
      float u[8];
#pragma unroll
      for (int i = 0; i < 8; ++i) {
        float v = fmaxf(xv[i][c] - tau[c], 0.0f);
        u[i] = v * v;
      }
      uint4 w;
      w.x = pk2bf(u[0], u[1]);
      w.y = pk2bf(u[2], u[3]);
      w.z = pk2bf(u[4], u[5]);
      w.w = pk2bf(u[6], u[7]);
      *(uint4*)&Bs[(g * 4 + c) * BS_STRIDE + j * 8] = w;
    }
  }
  __syncthreads();  // Bs complete (only barrier in the kernel)

  // ---- 2. GEMM, one (chunk, sub) at a time; in-register transpose store ----
#pragma unroll
  for (int c = 0; c < 2; ++c) {
#pragma unroll
    for (int sub = 0; sub < 2; ++sub) {
      const int b = c * 128 + wid * 32 + sub * 16 + row16;  // this lane's output col
      const unsigned short* xptr = xb2 + ((size_t)m * B_ + b) * D_ + quad * 8;
      short8 xfr[4];
#pragma unroll
      for (int ks = 0; ks < 4; ++ks) xfr[ks] = *(const short8*)(xptr + ks * 32);

      floatx4 acc[4];
#pragma unroll
      for (int cf = 0; cf < 4; ++cf) acc[cf] = (floatx4){0.f, 0.f, 0.f, 0.f};
#pragma unroll
      for (int cf = 0; cf < 4; ++cf) {
        short8 afr[4];
#pragma unroll
        for (int ks = 0; ks < 4; ++ks)
          afr[ks] = *(const short8*)&Bs[(cf * 16 + row16) * BS_STRIDE + ks * 32 + quad * 8];
#pragma unroll
        for (int ks = 0; ks < 4; ++ks)
          acc[cf] = __builtin_amdgcn_mfma_f32_16x16x32_bf16(afr[ks], xfr[ks], acc[cf], 0, 0, 0);
      }

      // pack: X[cf] = bf16x4 for t in [cf*16 + quad*4, +4) at col b
      unsigned X0x = pk2bf(acc[0][0], acc[0][1]), X0y = pk2bf(acc[0][2], acc[0][3]);
      unsigned X1x = pk2bf(acc[1][0], acc[1][1]), X1y = pk2bf(acc[1][2], acc[1][3]);
      unsigned X2x = pk2bf(acc[2][0], acc[2][1]), X2y = pk2bf(acc[2][2], acc[2][3]);
      unsigned X3x = pk2bf(acc[3][0], acc[3][1]), X3y = pk2bf(acc[3][2], acc[3][3]);

      // 4x4 butterfly transpose across quads (col preserved):
      // stage 1: quad bit1 <-> slot bit1 (lane xor 32)
      const bool hi2 = (quad & 2) != 0;
      unsigned s0x = hi2 ? X0x : X2x, s0y = hi2 ? X0y : X2y;
      unsigned s1x = hi2 ? X1x : X3x, s1y = hi2 ? X1y : X3y;
      unsigned r0x = __shfl_xor(s0x, 32), r0y = __shfl_xor(s0y, 32);
      unsigned r1x = __shfl_xor(s1x, 32), r1y = __shfl_xor(s1y, 32);
      unsigned A0x = hi2 ? r0x : X0x, A0y = hi2 ? r0y : X0y;
      unsigned A1x = hi2 ? r1x : X1x, A1y = hi2 ? r1y : X1y;
      unsigned A2x = hi2 ? X2x : r0x, A2y = hi2 ? X2y : r0y;
      unsigned A3x = hi2 ? X3x : r1x, A3y = hi2 ? X3y : r1y;
      // stage 2: quad bit0 <-> slot bit0 (lane xor 16)
      const bool odd = (quad & 1) != 0;
      unsigned t0x = odd ? A0x : A1x, t0y = odd ? A0y : A1y;
      unsigned t1x = odd ? A2x : A3x, t1y = odd ? A2y : A3y;
      unsigned u0x = __shfl_xor(t0x, 16), u0y = __shfl_xor(t0y, 16);
      unsigned u1x = __shfl_xor(t1x, 16), u1y = __shfl_xor(t1y, 16);
      uint4 w0, w1;
      w0.x = odd ? u0x : A0x;  w0.y = odd ? u0y : A0y;
      w0.z = odd ? A1x : u0x;  w0.w = odd ? A1y : u0y;
      w1.x = odd ? u1x : A2x;  w1.y = odd ? u1y : A2y;
      w1.z = odd ? A3x : u1x;  w1.w = odd ? A3y : u1y;

      // 32B per lane; quads 0..3 of a column cover 128B contiguous t-range
      unsigned short* dst = priors + (((size_t)n * B_ + b) * M_ + m) * T_ + quad * 16;
      *(uint4*)dst = w0;
      *(uint4*)(dst + 8) = w1;
    }
  }
}

// ---------------------------------------------------------------------------
// K2 (R20 = R17 verbatim): block = (n, g4); wave owns ONE b; DPP reductions;
// __launch_bounds__(256, 4). R19 PROVED (256,8) forces the ~90-VGPR live set
// to spill (FETCH 33->216MB, dur 2x). 64 VGPR at (256,4) does NOT spill.
// Do not touch the launch bounds here again.
// ---------------------------------------------------------------------------
__global__ __launch_bounds__(256, 4) void k_route(const unsigned short* __restrict__ priors,
                                                  const unsigned short* __restrict__ lhn,
                                                  const float* __restrict__ thrT,
                                                  const float* __restrict__ gamma,
                                                  const float* __restrict__ beta,
                                                  float* __restrict__ out) {
  const int n = blockIdx.x, g4 = blockIdx.y;
  const int tid = threadIdx.x;
  const int wid = tid >> 6, lane = tid & 63;
  const int col = lane & 15, quad = lane >> 4;

  __shared__ float probL[4][64];

  const int b = g4 * 4 + wid;  // wave's batch element

  const unsigned short* base = priors + ((size_t)n * B_ + b) * (M_ * T_);  // 8KB contiguous
  short8 afr[4][2];  // A[m = mt*16+col][k(t) = ks*32+quad*8+j]
#pragma unroll
  for (int mt = 0; mt < 4; ++mt)
#pragma unroll
    for (int ks = 0; ks < 2; ++ks)
      afr[mt][ks] = *(const short8*)(base + (mt * 16 + col) * T_ + ks * 32 + quad * 8);

  float thv = thrT[n * 64 + lane];

  float dis[4][4];
#pragma unroll
  for (int mt = 0; mt < 4; ++mt)
#pragma unroll
    for (int r = 0; r < 4; ++r) dis[mt][r] = 0.f;

#pragma unroll
  for (int s4 = 0; s4 < 4; ++s4) {
    floatx4 acc[4][2];
#pragma unroll
    for (int mt = 0; mt < 4; ++mt)
#pragma unroll
      for (int lt = 0; lt < 2; ++lt) acc[mt][lt] = (floatx4){0.f, 0.f, 0.f, 0.f};

#pragma unroll
    for (int lt = 0; lt < 2; ++lt) {
#pragma unroll
      for (int ks = 0; ks < 2; ++ks) {
        short8 bfr = *(const short8*)(lhn + (s4 * 32 + lt * 16 + col) * T_ + ks * 32 + quad * 8);
#pragma unroll
        for (int mt = 0; mt < 4; ++mt)
          acc[mt][lt] = __builtin_amdgcn_mfma_f32_16x16x32_bf16(afr[mt][ks], bfr, acc[mt][lt], 0, 0, 0);
      }
    }

#pragma unroll
    for (int mt = 0; mt < 4; ++mt)
#pragma unroll
      for (int lt = 0; lt < 2; ++lt)
#pragma unroll
        for (int r = 0; r < 4; ++r)
          acc[mt][lt][r] = frcp(1.0f + __expf(-acc[mt][lt][r]));

    float mc[2];
#pragma unroll
    for (int lt = 0; lt < 2; ++lt) {
      float s = 0.f;
#pragma unroll
      for (int mt = 0; mt < 4; ++mt)
#pragma unroll
        for (int r = 0; r < 4; ++r) s += acc[mt][lt][r];
      s += __shfl_xor(s, 16);
      s += __shfl_xor(s, 32);
      mc[lt] = s * (1.0f / 64.0f);
    }

#pragma unroll
    for (int mt = 0; mt < 4; ++mt)
#pragma unroll
      for (int r = 0; r < 4; ++r) {
        float s = 0.f;
#pragma unroll
        for (int lt = 0; lt < 2; ++lt) {
          float df = acc[mt][lt][r] - mc[lt];
          s = fmaf(df, df, s);
        }
        dis[mt][r] += s;
      }
  }

  // dis: reduce over col (16-lane rows) — DPP ladder
#pragma unroll
  for (int mt = 0; mt < 4; ++mt)
#pragma unroll
    for (int r = 0; r < 4; ++r) dis[mt][r] = rsum16(dis[mt][r]);

  float e[4][4];
  float mxw = 0.f;
#pragma unroll
  for (int mt = 0; mt < 4; ++mt)
#pragma unroll
    for (int r = 0; r < 4; ++r) {
      float th = __shfl(thv, mt * 16 + quad * 4 + r);
      float w = fmaxf(th * th - dis[mt][r] * (1.0f / 128.0f), 0.0f);
      e[mt][r] = w;
      mxw = fmaxf(mxw, w);
    }
  mxw = fmaxf(mxw, __shfl_xor(mxw, 16));
  mxw = fmaxf(mxw, __shfl_xor(mxw, 32));
  float ssum = 0.f;
#pragma unroll
  for (int mt = 0; mt < 4; ++mt)
#pragma unroll
    for (int r = 0; r < 4; ++r) {
      e[mt][r] = __expf(e[mt][r] - mxw);
      ssum += e[mt][r];
    }
  ssum += __shfl_xor(ssum, 16);
  ssum += __shfl_xor(ssum, 32);
  float inv = frcp(ssum);
  if (col == 0) {
#pragma unroll
    for (int mt = 0; mt < 4; ++mt)
#pragma unroll
      for (int r = 0; r < 4; ++r)
        probL[wid][mt * 16 + quad * 4 + r] = e[mt][r] * inv;
  }
  // same-wave LDS write->read: compiler inserts lgkmcnt wait (no barrier)

  float pr[4];
#pragma unroll
  for (int mt = 0; mt < 4; ++mt) pr[mt] = probL[wid][mt * 16 + col];

  float o[2][8];
#pragma unroll
  for (int ks = 0; ks < 2; ++ks)
#pragma unroll
    for (int j = 0; j < 8; ++j) o[ks][j] = 0.f;
#pragma unroll
  for (int mt = 0; mt < 4; ++mt)
#pragma unroll
    for (int ks = 0; ks < 2; ++ks)
#pragma unroll
      for (int j = 0; j < 8; ++j)
        o[ks][j] = fmaf(pr[mt], bf2f((unsigned short)afr[mt][ks][j]), o[ks][j]);
  // o: reduce over col (16-lane rows) — DPP ladder
#pragma unroll
  for (int ks = 0; ks < 2; ++ks)
#pragma unroll
    for (int j = 0; j < 8; ++j) o[ks][j] = rsum16(o[ks][j]);

  float mu = 0.f;
#pragma unroll
  for (int ks = 0; ks < 2; ++ks)
#pragma unroll
    for (int j = 0; j < 8; ++j) mu += o[ks][j];
  mu += __shfl_xor(mu, 16);
  mu += __shfl_xor(mu, 32);
  mu *= (1.0f / 64.0f);
  float var = 0.f;
#pragma unroll
  for (int ks = 0; ks < 2; ++ks)
#pragma unroll
    for (int j = 0; j < 8; ++j) {
      float d = o[ks][j] - mu;
      o[ks][j] = d;
      var = fmaf(d, d, var);
    }
  var += __shfl_xor(var, 16);
  var += __shfl_xor(var, 32);
  var *= (1.0f / 64.0f);
  float rstd = rsqrtf(var + 1e-5f);

  if (col == 0) {
    float* obase = out + ((size_t)b * N_ + n) * T_;
#pragma unroll
    for (int ks = 0; ks < 2; ++ks) {
      int tb = ks * 32 + quad * 8;
      float4 g0 = *(const float4*)(gamma + tb);
      float4 g1 = *(const float4*)(gamma + tb + 4);
      float4 b0 = *(const float4*)(beta + tb);
      float4 b1 = *(const float4*)(beta + tb + 4);
      float4 r0, r1;
      r0.x = o[ks][0] * rstd * g0.x + b0.x;
      r0.y = o[ks][1] * rstd * g0.y + b0.y;
      r0.z = o[ks][2] * rstd * g0.z + b0.z;
      r0.w = o[ks][3] * rstd * g0.w + b0.w;
      r1.x = o[ks][4] * rstd * g1.x + b1.x;
      r1.y = o[ks][5] * rstd * g1.y + b1.y;
      r1.z = o[ks][6] * rstd * g1.z + b1.z;
      r1.w = o[ks][7] * rstd * g1.w + b1.w;
      *(float4*)(obase + tb) = r0;
      *(float4*)(obase + tb + 4) = r1;
    }
  }
}

// ---------------------------------------------------------------------------
// Workspace layout (bytes):
//   priors [N][B][M][T]   bf16 : off 0,          67,108,864
//   xb2    [M][B][pi(D)]  bf16 : off 67,108,864,  4,194,304
//   LHn    [L][T]         bf16 : off 71,303,168,     16,384
//   thrT   [N][M]         fp32 : off 71,319,552,      8,192
// ---------------------------------------------------------------------------
extern "C" void kernel_launch(void* const* d_in, const int* in_sizes, int n_in,
                              void* d_out, int out_size, void* d_ws, size_t ws_size,
                              hipStream_t stream) {
  const float* x = (const float*)d_in[0];
  const float* rw = (const float*)d_in[1];
  const float* thr = (const float*)d_in[2];
  const float* leaves = (const float*)d_in[3];
  const float* gamma = (const float*)d_in[4];
  const float* beta = (const float*)d_in[5];
  float* out = (float*)d_out;

  char* ws = (char*)d_ws;
  unsigned short* priors = (unsigned short*)(ws);
  unsigned short* xb2 = (unsigned short*)(ws + 67108864);
  unsigned short* lhn = (unsigned short*)(ws + 71303168);
  float* thrT = (float*)(ws + 71319552);

  hipLaunchKernelGGL(k_prep, dim3(1026), dim3(256), 0, stream, x, leaves, xb2, lhn, thr, thrT);
  hipLaunchKernelGGL(k_wpriors, dim3(64, 32), dim3(256), 0, stream, xb2, rw, priors);
  hipLaunchKernelGGL(k_route, dim3(32, 64), dim3(256), 0, stream, priors, lhn, thrT, gamma, beta, out);
}